// Round 6
// baseline (1487.503 us; speedup 1.0000x reference)
//
#include <hip/hip_runtime.h>

#define BATCH 1024
#define SEQ   1024
#define FDIM  36
#define HID   20
#define G3    60
#define CR    64          // rows per LDS gi chunk
#define NCHUNK (SEQ/CR)   // 16

typedef float v2f __attribute__((ext_vector_type(2)));

__device__ __forceinline__ float fast_sigmoid(float x){
    return __builtin_amdgcn_rcpf(1.0f + __expf(-x));
}
__device__ __forceinline__ float fast_tanh(float x){
    return fmaf(-2.0f, __builtin_amdgcn_rcpf(1.0f + __expf(2.0f*x)), 1.0f);
}

// One block per TWO batch elements, 2 waves:
//  wave0 (consumer): encoder GRU then decoder GRU for batches A and B,
//                    instruction-interleaved (2 independent chains fill the
//                    ~60% idle issue slots measured in R10: VALUBusy 41%,
//                    1 wave/SIMD in decoder phase -> pure exposed latency).
//  wave1 (producer): embed/concat -> origin rows + gi = Wih1@x+bih1 into
//                    double-buffered LDS chunks for A then B (2x work,
//                    within its ~3x measured slack).
//
// Ledger of measured lessons:
//  R8: permlane gate relayout (2 dots/lane) = +143cy/step LOSS. Keep 1-dot.
//  R9: store-drain unroll + dsh pre-issue = NEUTRAL (latency already hidden).
//  R10: removing 20x readlane bcast dropped VALUBusy 58->41 at SAME duration
//       -> chain is latency-bound with idle issue slots; TLP=1/SIMD in
//       decoder phase. R11 converts idle slots into a 2nd batch chain (ILP).
//  R11 first submit: container failed twice (infra) -- resubmitted unchanged
//       after a fault audit (LDS 61.9KB ok, barriers uniform, stores benign,
//       indices in range, no spill risk).
//
// Decoder BB discipline: out2 store is unconditional via clamped column
// (kf=min(lane,35)); lanes>=36 compute bit-identical xv to lane 35 (clamped
// wfc row), so the same-address write is value-identical -> no exec-mask
// branch, both chains stay in one schedulable basic block.
// __launch_bounds__(128,1): VGPR cap 512 (no spill risk); residency is
// LDS-limited to 2 blocks/CU (61.5KB gbuf) = 4 waves/CU either way.
__global__ __launch_bounds__(128, 1)
void gru_fused(const float* __restrict__ x,
               const int* __restrict__ oh,
               const float* __restrict__ e0, const float* __restrict__ e1,
               const float* __restrict__ e2, const float* __restrict__ e3,
               const float* __restrict__ Wih1g, const float* __restrict__ Whh1g,
               const float* __restrict__ bih1g, const float* __restrict__ bhh1g,
               const float* __restrict__ Wih2g, const float* __restrict__ Whh2g,
               const float* __restrict__ bih2g, const float* __restrict__ bhh2g,
               const float* __restrict__ Wfcg,  const float* __restrict__ bfcg,
               float* __restrict__ origin, float* __restrict__ out2)
{
    __shared__ __align__(16) float gbuf[2][2][CR][G3]; // [batch][dbuf] 60KB
    __shared__ __align__(16) float psh[2][64];         // producer broadcast
    __shared__ __align__(16) float dsh[2][64];         // decoder x broadcast
    __shared__ __align__(16) float hsh[2][64];         // h broadcast

    const int lane   = threadIdx.x & 63;
    const bool is_enc = (threadIdx.x < 64);            // wave0 = consumer
    const int bb = __builtin_amdgcn_readfirstlane(blockIdx.x);
    const int b0 = 2 * bb, b1 = 2 * bb + 1;

    const int k = lane < G3 ? lane : G3 - 1;

    // ---- consumer cross-loop state ----
    float whh1[HID];
    float bh1 = 0.f;
    float hsA[HID], hsB[HID];
    float hvA = 0.0f, hvB = 0.0f;
    if (is_enc) {
        #pragma unroll
        for (int u = 0; u < HID; u++) whh1[u] = Whh1g[k * HID + u];
        bh1 = bhh1g[k];
        #pragma unroll
        for (int u = 0; u < HID; u++) { hsA[u] = 0.0f; hsB[u] = 0.0f; }
    }

    // ---- producer state ----
    const int j = lane;
    const float* tbl; int ohc, eshift, sub;
    if (j < 16)      { tbl = e0; ohc = 0; eshift = 2; sub = j - 12; }
    else if (j < 20) { tbl = e1; ohc = 1; eshift = 2; sub = j - 16; }
    else if (j < 28) { tbl = e2; ohc = 2; eshift = 3; sub = j - 20; }
    else             { tbl = e3; ohc = 3; eshift = 3; sub = j - 28; }
    if (sub < 0) sub = 0;
    if (sub > 7) sub = 7;
    const bool from_x = (j < 12);
    const float* pa = from_x ? (x + j) : (tbl + sub);
    v2f w1p[FDIM/2]; float bi1 = 0.f;
    if (!is_enc) {
        #pragma unroll
        for (int q = 0; q < FDIM/2; q++) w1p[q] = ((const v2f*)(Wih1g + k * FDIM))[q];
        bi1 = bih1g[k];
    }

// h broadcast via LDS (R10 form): unconditional write, 5 broadcast float4
// reads -> HS in VGPRs. Same-wave DS ordering, no barrier.
#define HS_BCAST(P, HVAL, HS) do {                                           \
        hsh[P][lane] = (HVAL);                                               \
        const float4* hq_ = (const float4*)hsh[P];                           \
        float4 t0_ = hq_[0], t1_ = hq_[1], t2_ = hq_[2], t3_ = hq_[3],       \
               t4_ = hq_[4];                                                 \
        HS[0]=t0_.x;  HS[1]=t0_.y;  HS[2]=t0_.z;  HS[3]=t0_.w;               \
        HS[4]=t1_.x;  HS[5]=t1_.y;  HS[6]=t1_.z;  HS[7]=t1_.w;               \
        HS[8]=t2_.x;  HS[9]=t2_.y;  HS[10]=t2_.z; HS[11]=t2_.w;              \
        HS[12]=t3_.x; HS[13]=t3_.y; HS[14]=t3_.z; HS[15]=t3_.w;              \
        HS[16]=t4_.x; HS[17]=t4_.y; HS[18]=t4_.z; HS[19]=t4_.w;              \
    } while (0)

#define GATE_STEP(GIV, HS, HVAR, P) do {                                     \
        float h0 = bh1, h1 = 0.f, h2 = 0.f, h3 = 0.f;                        \
        _Pragma("unroll")                                                    \
        for (int uu = 0; uu < HID; uu += 4) {                                \
            h0 = fmaf(whh1[uu + 0], HS[uu + 0], h0);                         \
            h1 = fmaf(whh1[uu + 1], HS[uu + 1], h1);                         \
            h2 = fmaf(whh1[uu + 2], HS[uu + 2], h2);                         \
            h3 = fmaf(whh1[uu + 3], HS[uu + 3], h3);                         \
        }                                                                    \
        float gh = (h0 + h1) + (h2 + h3);                                    \
        float v   = (GIV) + gh;                                              \
        float in_ = __shfl((GIV),(lane + 40) & 63);                          \
        float hn  = __shfl(gh,   (lane + 40) & 63);                          \
        float s = fast_sigmoid(v);                                           \
        float z = __shfl(s, (lane + 20) & 63);                               \
        float n = fast_tanh(fmaf(s, hn, in_));                               \
        HVAR = n + z * (HVAR - n);                                           \
        HS_BCAST(P, HVAR, HS);                                               \
    } while (0)

#define CONSUME_CHUNK(CB) do {                                               \
        const float* gpA = &gbuf[0][CB][0][k];                               \
        const float* gpB = &gbuf[1][CB][0][k];                               \
        float gA0 = gpA[0],  gB0 = gpB[0];                                   \
        float gA1 = gpA[G3], gB1 = gpB[G3];                                  \
        _Pragma("unroll 1")                                                  \
        for (int i = 0; i < CR; i += 2) {                                    \
            float eA = gA0, eB = gB0, oA = gA1, oB = gB1;                    \
            if (i < CR - 2) { gA0 = gpA[(i + 2) * G3]; gB0 = gpB[(i + 2) * G3]; } \
            GATE_STEP(eA, hsA, hvA, 0);                                      \
            GATE_STEP(eB, hsB, hvB, 1);                                      \
            if (i < CR - 2) { gA1 = gpA[(i + 3) * G3]; gB1 = gpB[(i + 3) * G3]; } \
            GATE_STEP(oA, hsA, hvA, 0);                                      \
            GATE_STEP(oB, hsB, hvB, 1);                                      \
        }                                                                    \
    } while (0)

    // ---------------- pipelined chunk loop ----------------
    #pragma unroll 1
    for (int c = 0; c < NCHUNK; ++c) {
        if (!is_enc) {
            #pragma unroll 1
            for (int p = 0; p < 2; ++p) {
                const int rbase = (p ? b1 : b0) * SEQ + c * CR;
                float* gdst = &gbuf[p][c & 1][0][0];
                const float4* xp4 = (const float4*)psh[p];
                #pragma unroll 1
                for (int g = 0; g < CR / 8; ++g) {
                    int ohv[8];
                    #pragma unroll
                    for (int n = 0; n < 8; n++)
                        ohv[n] = oh[(rbase + 8 * g + n) * 4 + ohc];
                    float valv[8];
                    #pragma unroll
                    for (int n = 0; n < 8; n++) {
                        int R = rbase + 8 * g + n;
                        int off = from_x ? (R * 12) : (ohv[n] << eshift);
                        valv[n] = pa[off];
                    }
                    #pragma unroll
                    for (int n = 0; n < 8; n++) {
                        const int i = 8 * g + n;
                        const size_t R = (size_t)(rbase + i);
                        psh[p][lane] = valv[n];       // same-wave DS ordering
                        if (lane < FDIM) origin[R * FDIM + lane] = valv[n];
                        v2f a0 = {bi1, 0.f}, a1 = {0.f, 0.f};
                        #pragma unroll
                        for (int q = 0; q < 9; q++) {
                            float4 xv4 = xp4[q];
                            v2f xlo = {xv4.x, xv4.y}, xhi = {xv4.z, xv4.w};
                            a0 = __builtin_elementwise_fma(w1p[2*q],     xlo, a0);
                            a1 = __builtin_elementwise_fma(w1p[2*q + 1], xhi, a1);
                        }
                        float gg = (a0.x + a1.x) + (a0.y + a1.y);
                        if (lane < G3) gdst[i * G3 + lane] = gg;
                    }
                }
            }
        } else if (c > 0) {
            CONSUME_CHUNK((c - 1) & 1);
        }
        __syncthreads();
    }
    if (!is_enc) return;              // producer done (after its final barrier)

    CONSUME_CHUNK((NCHUNK - 1) & 1);  // last chunk; no further barriers

    // ---- decoder weights loaded only now ----
    const int kf = lane < FDIM ? lane : FDIM - 1;
    float whh2[HID], wfc[HID];
    v2f wih2p[FDIM/2];
    #pragma unroll
    for (int q = 0; q < FDIM/2; q++) wih2p[q] = ((const v2f*)(Wih2g + k * FDIM))[q];
    #pragma unroll
    for (int u = 0; u < HID; u++) whh2[u] = Whh2g[k * HID + u];
    #pragma unroll
    for (int u = 0; u < HID; u++) wfc[u] = Wfcg[kf * HID + u];
    const float bi2 = bih2g[k], bh2 = bhh2g[k];
    const float bf  = bfcg[kf];

    // ---------------- handoff (both batches) ----------------
    float hvdA = fast_tanh(hvA);
    float hvdB = fast_tanh(hvB);
    HS_BCAST(0, hvdA, hsA);
    HS_BCAST(1, hvdB, hsB);

    // clamped-column store pointers: lanes >=36 duplicate lane 35's value
    // (same wfc row kf=35, same hs) -> same-address same-value write, benign.
    float* orowA = out2 + ((size_t)b0 * SEQ + (SEQ - 1)) * FDIM + kf;
    float* orowB = out2 + ((size_t)b1 * SEQ + (SEQ - 1)) * FDIM + kf;

#define FC_STEP(HS, XOUT) do {                                               \
        float f0 = bf, f1 = 0.f, f2 = 0.f, f3 = 0.f;                         \
        _Pragma("unroll")                                                    \
        for (int u = 0; u < HID; u += 4) {                                   \
            f0 = fmaf(wfc[u + 0], HS[u + 0], f0);                            \
            f1 = fmaf(wfc[u + 1], HS[u + 1], f1);                            \
            f2 = fmaf(wfc[u + 2], HS[u + 2], f2);                            \
            f3 = fmaf(wfc[u + 3], HS[u + 3], f3);                            \
        }                                                                    \
        XOUT = fast_tanh((f0 + f1) + (f2 + f3));                             \
    } while (0)

    float xvA, xvB;
    FC_STEP(hsA, xvA);
    FC_STEP(hsB, xvB);
    dsh[0][lane] = xvA;
    dsh[1][lane] = xvB;
    *orowA = xvA;
    *orowB = xvB;

// One decoder step for batch P. Reads x from dsh[P] (written previous step,
// same-wave ordering), math bit-identical to R10.
#define DEC_STEP(P, HS, HVD, OROW) do {                                      \
        const v2f* xp_ = (const v2f*)dsh[P];                                 \
        v2f xs2[FDIM/2];                                                     \
        _Pragma("unroll")                                                    \
        for (int q = 0; q < FDIM/2; q++) xs2[q] = xp_[q];                    \
        float h0 = bh2, h1 = 0.f, h2 = 0.f, h3 = 0.f;                        \
        _Pragma("unroll")                                                    \
        for (int u = 0; u < HID; u += 4) {                                   \
            h0 = fmaf(whh2[u + 0], HS[u + 0], h0);                           \
            h1 = fmaf(whh2[u + 1], HS[u + 1], h1);                           \
            h2 = fmaf(whh2[u + 2], HS[u + 2], h2);                           \
            h3 = fmaf(whh2[u + 3], HS[u + 3], h3);                           \
        }                                                                    \
        float gh = (h0 + h1) + (h2 + h3);                                    \
        v2f accA = {bi2, 0.f}, accB = {0.f, 0.f};                            \
        _Pragma("unroll")                                                    \
        for (int q = 0; q < FDIM/2; q += 2) {                                \
            accA = __builtin_elementwise_fma(wih2p[q],     xs2[q],     accA); \
            accB = __builtin_elementwise_fma(wih2p[q + 1], xs2[q + 1], accB); \
        }                                                                    \
        float gi = (accA.x + accB.x) + (accA.y + accB.y);                    \
        float v   = gi + gh;                                                 \
        float in_ = __shfl(gi, (lane + 40) & 63);                            \
        float hn  = __shfl(gh, (lane + 40) & 63);                            \
        float s = fast_sigmoid(v);                                           \
        float z = __shfl(s, (lane + 20) & 63);                               \
        float n = fast_tanh(fmaf(s, hn, in_));                               \
        float hraw = n + z * (HVD - n);                                      \
        HVD = fast_tanh(hraw);                                               \
        HS_BCAST(P, HVD, HS);                                                \
        float xnew;                                                          \
        FC_STEP(HS, xnew);                                                   \
        OROW -= FDIM;                                                        \
        dsh[P][lane] = xnew;                                                 \
        *OROW = xnew;                                                        \
    } while (0)

    // ---------------- decoder: A and B chains interleaved ----------------
    #pragma unroll 1
    for (int d = 1; d < SEQ; ++d) {
        DEC_STEP(0, hsA, hvdA, orowA);
        DEC_STEP(1, hsB, hvdB, orowB);
    }
}

extern "C" void kernel_launch(void* const* d_in, const int* in_sizes, int n_in,
                              void* d_out, int out_size, void* d_ws, size_t ws_size,
                              hipStream_t stream) {
    const float* x    = (const float*)d_in[0];
    const int*   oh   = (const int*)d_in[1];
    const float* e0   = (const float*)d_in[2];
    const float* e1   = (const float*)d_in[3];
    const float* e2   = (const float*)d_in[4];
    const float* e3   = (const float*)d_in[5];
    const float* Wih1 = (const float*)d_in[6];
    const float* Whh1 = (const float*)d_in[7];
    const float* bih1 = (const float*)d_in[8];
    const float* bhh1 = (const float*)d_in[9];
    const float* Wih2 = (const float*)d_in[10];
    const float* Whh2 = (const float*)d_in[11];
    const float* bih2 = (const float*)d_in[12];
    const float* bhh2 = (const float*)d_in[13];
    const float* Wfc  = (const float*)d_in[14];
    const float* bfc  = (const float*)d_in[15];

    float* out    = (float*)d_out;
    float* origin = out;                                // output 0: (B,S,F)
    float* out2   = out + (size_t)BATCH * SEQ * FDIM;   // output 1: (B,S,F)

    gru_fused<<<BATCH/2, 128, 0, stream>>>(x, oh, e0, e1, e2, e3,
                                           Wih1, Whh1, bih1, bhh1,
                                           Wih2, Whh2, bih2, bhh2,
                                           Wfc, bfc, origin, out2);
}

// Round 7
// 1243.749 us; speedup vs baseline: 1.1960x; 1.1960x over previous
//
#include <hip/hip_runtime.h>

#define BATCH 1024
#define SEQ   1024
#define FDIM  36
#define HID   20
#define G3    60
#define CR    64          // rows per LDS gi chunk
#define NCHUNK (SEQ/CR)   // 16

typedef float v2f __attribute__((ext_vector_type(2)));

__device__ __forceinline__ float fast_sigmoid(float x){
    return __builtin_amdgcn_rcpf(1.0f + __expf(-x));
}
__device__ __forceinline__ float fast_tanh(float x){
    return fmaf(-2.0f, __builtin_amdgcn_rcpf(1.0f + __expf(2.0f*x)), 1.0f);
}

#define READLANE_F(v, u) __int_as_float(__builtin_amdgcn_readlane(__float_as_int(v), (u)))

// One block per batch element, 2 waves (R6-proven 747us skeleton):
//  wave0 (consumer): encoder GRU then decoder GRU (gate-row-major, readlane h-bcast)
//  wave1 (producer): embed/concat -> origin rows + gi = Wih1@x+bih1 into a
//                    double-buffered LDS chunk. __syncthreads pipelines.
//
// Ledger of measured lessons:
//  R8:  permlane gate relayout (2 dots/lane) = +143cy/step LOSS. Keep 1-dot.
//  R9:  store-drain unroll + dsh pre-issue = NEUTRAL (latency already hidden).
//  R10: readlane-h ~= LDS-bcast-h (swap neutral); VALUBusy 58->41 at same
//       duration -> chain latency-bound with idle issue slots.
//  R11: pairing 2 chains/wave = 1.67x per pair (33% overlap) + half the SIMDs
//       idle -> shared in-order lgkmcnt can't interleave DS-heavy chains.
//       Pairing requires a DS-minimal step. Grid stays 1024.
//  R12 (this round): decoder-only -- replace the dsh x round-trip
//       (write -> in-order wait -> 9x ds_read_b128, ~250-300cy on the chain)
//       with a 36x ds_bpermute ROTATION: lane k uses pre-rotated weights
//       wihrot[i] = Wih2[k][(lane+i)%36] and addresses xaddr[i]; bpermutes
//       of the previous x issue at step top (no write-retire gap) and
//       overlap the gh dot. dsh is deleted. Encoder/producer untouched.
//
// Register discipline (R6 lesson): decoder weights/addresses are materialized
// AFTER the chunk loop (live range must not span it). __launch_bounds__(128,2):
// 256-VGPR cap -> no scratch spill (est ~190 live in decoder).
__global__ __launch_bounds__(128, 2)
void gru_fused(const float* __restrict__ x,
               const int* __restrict__ oh,
               const float* __restrict__ e0, const float* __restrict__ e1,
               const float* __restrict__ e2, const float* __restrict__ e3,
               const float* __restrict__ Wih1g, const float* __restrict__ Whh1g,
               const float* __restrict__ bih1g, const float* __restrict__ bhh1g,
               const float* __restrict__ Wih2g, const float* __restrict__ Whh2g,
               const float* __restrict__ bih2g, const float* __restrict__ bhh2g,
               const float* __restrict__ Wfcg,  const float* __restrict__ bfcg,
               float* __restrict__ origin, float* __restrict__ out2)
{
    __shared__ __align__(16) float gbuf[2][CR][G3];  // 30 KB gi double buffer
    __shared__ __align__(16) float psh[64];          // producer broadcast scratch

    const int lane   = threadIdx.x & 63;
    const bool is_enc = (threadIdx.x < 64);          // wave0 = consumer
    const int b = __builtin_amdgcn_readfirstlane(blockIdx.x);

    const int k = lane < G3 ? lane : G3 - 1;

    // ---- consumer cross-loop state (kept minimal: whh1 + hs only) ----
    float whh1[HID];
    float bh1 = 0.f;
    float hs[HID];
    float hv = 0.0f;
    if (is_enc) {
        #pragma unroll
        for (int u = 0; u < HID; u++) whh1[u] = Whh1g[k * HID + u];
        bh1 = bhh1g[k];
        #pragma unroll
        for (int u = 0; u < HID; u++) hs[u] = 0.0f;
    }

    // ---- producer state ----
    const int j = lane;
    const float* tbl; int ohc, eshift, sub;
    if (j < 16)      { tbl = e0; ohc = 0; eshift = 2; sub = j - 12; }
    else if (j < 20) { tbl = e1; ohc = 1; eshift = 2; sub = j - 16; }
    else if (j < 28) { tbl = e2; ohc = 2; eshift = 3; sub = j - 20; }
    else             { tbl = e3; ohc = 3; eshift = 3; sub = j - 28; }
    if (sub < 0) sub = 0;
    if (sub > 7) sub = 7;
    const bool from_x = (j < 12);
    const float* pa = from_x ? (x + j) : (tbl + sub);
    v2f w1p[FDIM/2]; float bi1 = 0.f;
    if (!is_enc) {
        #pragma unroll
        for (int q = 0; q < FDIM/2; q++) w1p[q] = ((const v2f*)(Wih1g + k * FDIM))[q];
        bi1 = bih1g[k];
    }

#define GATE_STEP(GIV, WHH, BH, HVAR) do {                                   \
        float h0 = BH, h1 = 0.f, h2 = 0.f, h3 = 0.f;                         \
        _Pragma("unroll")                                                    \
        for (int uu = 0; uu < HID; uu += 4) {                                \
            h0 = fmaf(WHH[uu + 0], hs[uu + 0], h0);                          \
            h1 = fmaf(WHH[uu + 1], hs[uu + 1], h1);                          \
            h2 = fmaf(WHH[uu + 2], hs[uu + 2], h2);                          \
            h3 = fmaf(WHH[uu + 3], hs[uu + 3], h3);                          \
        }                                                                    \
        float gh = (h0 + h1) + (h2 + h3);                                    \
        float v   = (GIV) + gh;                                              \
        float vz  = __shfl(v,    (lane + 20) & 63);                          \
        float in_ = __shfl((GIV),(lane + 40) & 63);                          \
        float hn  = __shfl(gh,   (lane + 40) & 63);                          \
        float r = fast_sigmoid(v);                                           \
        float z = fast_sigmoid(vz);                                          \
        float n = fast_tanh(fmaf(r, hn, in_));                               \
        HVAR = n + z * (HVAR - n);                                           \
        _Pragma("unroll")                                                    \
        for (int uu = 0; uu < HID; uu++) hs[uu] = READLANE_F(HVAR, uu);      \
    } while (0)

#define CONSUME_CHUNK(CB) do {                                               \
        const float* gp = &gbuf[CB][0][k];                                   \
        float ga = gp[0], gbv = gp[G3];                                      \
        _Pragma("unroll 1")                                                  \
        for (int i = 0; i < CR; i += 2) {                                    \
            float ge = ga, go = gbv;                                         \
            if (i < CR - 2) ga = gp[(i + 2) * G3];                           \
            GATE_STEP(ge, whh1, bh1, hv);                                    \
            if (i < CR - 2) gbv = gp[(i + 3) * G3];                          \
            GATE_STEP(go, whh1, bh1, hv);                                    \
        }                                                                    \
    } while (0)

    // ---------------- pipelined chunk loop ----------------
    #pragma unroll 1
    for (int c = 0; c < NCHUNK; ++c) {
        if (!is_enc) {
            const int rbase = b * SEQ + c * CR;
            float* gdst = &gbuf[c & 1][0][0];
            const float4* xp4 = (const float4*)psh;
            #pragma unroll 1
            for (int g = 0; g < CR / 8; ++g) {
                int ohv[8];
                #pragma unroll
                for (int n = 0; n < 8; n++)
                    ohv[n] = oh[(rbase + 8 * g + n) * 4 + ohc];
                float valv[8];
                #pragma unroll
                for (int n = 0; n < 8; n++) {
                    int R = rbase + 8 * g + n;
                    int off = from_x ? (R * 12) : (ohv[n] << eshift);
                    valv[n] = pa[off];
                }
                #pragma unroll
                for (int n = 0; n < 8; n++) {
                    const int i = 8 * g + n;
                    const size_t R = (size_t)(rbase + i);
                    psh[lane] = valv[n];              // same-wave DS ordering
                    if (lane < FDIM) origin[R * FDIM + lane] = valv[n];
                    v2f a0 = {bi1, 0.f}, a1 = {0.f, 0.f};
                    #pragma unroll
                    for (int q = 0; q < 9; q++) {
                        float4 xv4 = xp4[q];
                        v2f xlo = {xv4.x, xv4.y}, xhi = {xv4.z, xv4.w};
                        a0 = __builtin_elementwise_fma(w1p[2*q],     xlo, a0);
                        a1 = __builtin_elementwise_fma(w1p[2*q + 1], xhi, a1);
                    }
                    float gg = (a0.x + a1.x) + (a0.y + a1.y);
                    if (lane < G3) gdst[i * G3 + lane] = gg;
                }
            }
        } else if (c > 0) {
            CONSUME_CHUNK((c - 1) & 1);
        }
        __syncthreads();
    }
    if (!is_enc) return;              // producer done (after its final barrier)

    CONSUME_CHUNK((NCHUNK - 1) & 1);  // last chunk; no further barriers

    // ---- decoder weights / rotation tables loaded only now ----
    const int kf = lane < FDIM ? lane : FDIM - 1;
    float whh2[HID], wfc[HID];
    #pragma unroll
    for (int u = 0; u < HID; u++) whh2[u] = Whh2g[k * HID + u];
    #pragma unroll
    for (int u = 0; u < HID; u++) wfc[u] = Wfcg[kf * HID + u];
    const float bi2 = bih2g[k], bh2 = bhh2g[k];
    const float bf  = bfcg[kf];

    // R12 x-rotation setup: idx_i = (lane+i)%36; xaddr = byte addr for
    // ds_bpermute; wihrot[i] = Wih2[k][idx_i] so gi_k = bi2 + sum_i w*xrot.
    int r36 = lane; if (r36 >= FDIM) r36 -= FDIM;    // lane % 36 (lane<64)
    int   xaddr[FDIM];
    float wihrot[FDIM];
    #pragma unroll
    for (int i = 0; i < FDIM; i++) {
        int idx = r36 + i; if (idx >= FDIM) idx -= FDIM;
        xaddr[i]  = idx << 2;
        wihrot[i] = Wih2g[k * FDIM + idx];
    }

    // ---------------- handoff ----------------
    float hvd = fast_tanh(hv);
    #pragma unroll
    for (int u = 0; u < HID; u++) hs[u] = READLANE_F(hvd, u);

    float* orow = out2 + ((size_t)b * SEQ + (SEQ - 1)) * FDIM;

    float xv;
    {
        float f0 = bf, f1 = 0.f, f2 = 0.f, f3 = 0.f;
        #pragma unroll
        for (int u = 0; u < HID; u += 4) {
            f0 = fmaf(wfc[u + 0], hs[u + 0], f0);
            f1 = fmaf(wfc[u + 1], hs[u + 1], f1);
            f2 = fmaf(wfc[u + 2], hs[u + 2], f2);
            f3 = fmaf(wfc[u + 3], hs[u + 3], f3);
        }
        xv = fast_tanh((f0 + f1) + (f2 + f3));
    }
    if (lane < FDIM) orow[lane] = xv;

    // ---------------- decoder (readlane-h, bpermute-rotation x, no LDS rt) ----
    #pragma unroll 1
    for (int d = 1; d < SEQ; ++d) {
        orow -= FDIM;
        // 1. issue all 36 rotation bpermutes of previous x (independent, DS-pipelined)
        const int xvi = __float_as_int(xv);
        float xr[FDIM];
        #pragma unroll
        for (int i = 0; i < FDIM; i++)
            xr[i] = __int_as_float(__builtin_amdgcn_ds_bpermute(xaddr[i], xvi));
        // 2. gh dot (pure VALU, overlaps bpermute latency)
        float h0 = bh2, h1 = 0.f, h2 = 0.f, h3 = 0.f;
        #pragma unroll
        for (int u = 0; u < HID; u += 4) {
            h0 = fmaf(whh2[u + 0], hs[u + 0], h0);
            h1 = fmaf(whh2[u + 1], hs[u + 1], h1);
            h2 = fmaf(whh2[u + 2], hs[u + 2], h2);
            h3 = fmaf(whh2[u + 3], hs[u + 3], h3);
        }
        float gh = (h0 + h1) + (h2 + h3);
        // 3. gi from rotated x
        float c0 = bi2, c1 = 0.f, c2 = 0.f, c3 = 0.f;
        #pragma unroll
        for (int i = 0; i < FDIM; i += 4) {
            c0 = fmaf(wihrot[i + 0], xr[i + 0], c0);
            c1 = fmaf(wihrot[i + 1], xr[i + 1], c1);
            c2 = fmaf(wihrot[i + 2], xr[i + 2], c2);
            c3 = fmaf(wihrot[i + 3], xr[i + 3], c3);
        }
        float gi = (c0 + c1) + (c2 + c3);
        // 4. gates (R6 exact form)
        float v   = gi + gh;
        float vz  = __shfl(v,  (lane + 20) & 63);
        float in_ = __shfl(gi, (lane + 40) & 63);
        float hn  = __shfl(gh, (lane + 40) & 63);
        float r = fast_sigmoid(v);
        float z = fast_sigmoid(vz);
        float n = fast_tanh(fmaf(r, hn, in_));
        float hraw = n + z * (hvd - n);
        hvd = fast_tanh(hraw);
        #pragma unroll
        for (int u = 0; u < HID; u++) hs[u] = READLANE_F(hvd, u);
        // 5. FC -> new x
        float f0 = bf, f1 = 0.f, f2 = 0.f, f3 = 0.f;
        #pragma unroll
        for (int u = 0; u < HID; u += 4) {
            f0 = fmaf(wfc[u + 0], hs[u + 0], f0);
            f1 = fmaf(wfc[u + 1], hs[u + 1], f1);
            f2 = fmaf(wfc[u + 2], hs[u + 2], f2);
            f3 = fmaf(wfc[u + 3], hs[u + 3], f3);
        }
        xv = fast_tanh((f0 + f1) + (f2 + f3));
        if (lane < FDIM) orow[lane] = xv;
    }
}

extern "C" void kernel_launch(void* const* d_in, const int* in_sizes, int n_in,
                              void* d_out, int out_size, void* d_ws, size_t ws_size,
                              hipStream_t stream) {
    const float* x    = (const float*)d_in[0];
    const int*   oh   = (const int*)d_in[1];
    const float* e0   = (const float*)d_in[2];
    const float* e1   = (const float*)d_in[3];
    const float* e2   = (const float*)d_in[4];
    const float* e3   = (const float*)d_in[5];
    const float* Wih1 = (const float*)d_in[6];
    const float* Whh1 = (const float*)d_in[7];
    const float* bih1 = (const float*)d_in[8];
    const float* bhh1 = (const float*)d_in[9];
    const float* Wih2 = (const float*)d_in[10];
    const float* Whh2 = (const float*)d_in[11];
    const float* bih2 = (const float*)d_in[12];
    const float* bhh2 = (const float*)d_in[13];
    const float* Wfc  = (const float*)d_in[14];
    const float* bfc  = (const float*)d_in[15];

    float* out    = (float*)d_out;
    float* origin = out;                                // output 0: (B,S,F)
    float* out2   = out + (size_t)BATCH * SEQ * FDIM;   // output 1: (B,S,F)

    gru_fused<<<BATCH, 128, 0, stream>>>(x, oh, e0, e1, e2, e3,
                                         Wih1, Whh1, bih1, bhh1,
                                         Wih2, Whh2, bih2, bhh2,
                                         Wfc, bfc, origin, out2);
}

// Round 8
// 1068.712 us; speedup vs baseline: 1.3919x; 1.1638x over previous
//
#include <hip/hip_runtime.h>

#define BATCH 1024
#define SEQ   1024
#define FDIM  36
#define HID   20
#define G3    60
#define CR    64          // rows per LDS gi chunk
#define NCHUNK (SEQ/CR)   // 16

typedef float v2f __attribute__((ext_vector_type(2)));

__device__ __forceinline__ float fast_sigmoid(float x){
    return __builtin_amdgcn_rcpf(1.0f + __expf(-x));
}
__device__ __forceinline__ float fast_tanh(float x){
    return fmaf(-2.0f, __builtin_amdgcn_rcpf(1.0f + __expf(2.0f*x)), 1.0f);
}

#define READLANE_F(v, u) __int_as_float(__builtin_amdgcn_readlane(__float_as_int(v), (u)))

// One block per batch element, 2 waves (R6-proven 747us skeleton):
//  wave0 (consumer): encoder GRU then decoder GRU (gate-row-major, readlane h-bcast)
//  wave1 (producer): embed/concat -> origin rows + gi = Wih1@x+bih1 into a
//                    double-buffered LDS chunk. __syncthreads pipelines.
//
// Ledger of measured lessons:
//  R8:  permlane gate relayout (2 dots/lane) = +143cy/step LOSS. Keep 1-dot.
//  R9:  store-drain unroll + dsh pre-issue = NEUTRAL (latency already hidden).
//  R10: readlane-h ~= LDS-bcast-h (swap neutral; 20 readlanes/step are hidden).
//  R11: pairing 2 DS-heavy chains/wave = 1.67x per pair + half SIMDs idle.
//  R12: ds_bpermute rotation = +270us, SQ_LDS_BANK_CONFLICT 0 -> 6.5e7.
//       bpermute only cheap as broadcast/identity; rotations serialize.
//  R13 (this round): decoder-only -- replace the dsh x round-trip
//       (ds_write -> in-order wait -> 9x ds_read_b128, ~250cy DS on the chain)
//       with 36x v_readlane -> SGPR, consumed directly by VGPR*SGPR FMAs
//       (~80cy, VALU-pipelined, no DS). R7's readlane-x blame is suspect
//       (bundled 3 changes; R10 exonerated readlanes in this skeleton).
//       Clean single-variable test. dsh deleted; decoder has ZERO DS ops
//       besides the 3 proven gate shfls.
//
// Register discipline (R6 lesson): decoder weights are loaded AFTER the chunk
// loop (live range must not span it). __launch_bounds__(128,2): 256-VGPR cap.
__global__ __launch_bounds__(128, 2)
void gru_fused(const float* __restrict__ x,
               const int* __restrict__ oh,
               const float* __restrict__ e0, const float* __restrict__ e1,
               const float* __restrict__ e2, const float* __restrict__ e3,
               const float* __restrict__ Wih1g, const float* __restrict__ Whh1g,
               const float* __restrict__ bih1g, const float* __restrict__ bhh1g,
               const float* __restrict__ Wih2g, const float* __restrict__ Whh2g,
               const float* __restrict__ bih2g, const float* __restrict__ bhh2g,
               const float* __restrict__ Wfcg,  const float* __restrict__ bfcg,
               float* __restrict__ origin, float* __restrict__ out2)
{
    __shared__ __align__(16) float gbuf[2][CR][G3];  // 30 KB gi double buffer
    __shared__ __align__(16) float psh[64];          // producer broadcast scratch

    const int lane   = threadIdx.x & 63;
    const bool is_enc = (threadIdx.x < 64);          // wave0 = consumer
    const int b = __builtin_amdgcn_readfirstlane(blockIdx.x);

    const int k = lane < G3 ? lane : G3 - 1;

    // ---- consumer cross-loop state (kept minimal: whh1 + hs only) ----
    float whh1[HID];
    float bh1 = 0.f;
    float hs[HID];
    float hv = 0.0f;
    if (is_enc) {
        #pragma unroll
        for (int u = 0; u < HID; u++) whh1[u] = Whh1g[k * HID + u];
        bh1 = bhh1g[k];
        #pragma unroll
        for (int u = 0; u < HID; u++) hs[u] = 0.0f;
    }

    // ---- producer state ----
    const int j = lane;
    const float* tbl; int ohc, eshift, sub;
    if (j < 16)      { tbl = e0; ohc = 0; eshift = 2; sub = j - 12; }
    else if (j < 20) { tbl = e1; ohc = 1; eshift = 2; sub = j - 16; }
    else if (j < 28) { tbl = e2; ohc = 2; eshift = 3; sub = j - 20; }
    else             { tbl = e3; ohc = 3; eshift = 3; sub = j - 28; }
    if (sub < 0) sub = 0;
    if (sub > 7) sub = 7;
    const bool from_x = (j < 12);
    const float* pa = from_x ? (x + j) : (tbl + sub);
    v2f w1p[FDIM/2]; float bi1 = 0.f;
    if (!is_enc) {
        #pragma unroll
        for (int q = 0; q < FDIM/2; q++) w1p[q] = ((const v2f*)(Wih1g + k * FDIM))[q];
        bi1 = bih1g[k];
    }

#define GATE_STEP(GIV, WHH, BH, HVAR) do {                                   \
        float h0 = BH, h1 = 0.f, h2 = 0.f, h3 = 0.f;                         \
        _Pragma("unroll")                                                    \
        for (int uu = 0; uu < HID; uu += 4) {                                \
            h0 = fmaf(WHH[uu + 0], hs[uu + 0], h0);                          \
            h1 = fmaf(WHH[uu + 1], hs[uu + 1], h1);                          \
            h2 = fmaf(WHH[uu + 2], hs[uu + 2], h2);                          \
            h3 = fmaf(WHH[uu + 3], hs[uu + 3], h3);                          \
        }                                                                    \
        float gh = (h0 + h1) + (h2 + h3);                                    \
        float v   = (GIV) + gh;                                              \
        float vz  = __shfl(v,    (lane + 20) & 63);                          \
        float in_ = __shfl((GIV),(lane + 40) & 63);                          \
        float hn  = __shfl(gh,   (lane + 40) & 63);                          \
        float r = fast_sigmoid(v);                                           \
        float z = fast_sigmoid(vz);                                          \
        float n = fast_tanh(fmaf(r, hn, in_));                               \
        HVAR = n + z * (HVAR - n);                                           \
        _Pragma("unroll")                                                    \
        for (int uu = 0; uu < HID; uu++) hs[uu] = READLANE_F(HVAR, uu);      \
    } while (0)

#define CONSUME_CHUNK(CB) do {                                               \
        const float* gp = &gbuf[CB][0][k];                                   \
        float ga = gp[0], gbv = gp[G3];                                      \
        _Pragma("unroll 1")                                                  \
        for (int i = 0; i < CR; i += 2) {                                    \
            float ge = ga, go = gbv;                                         \
            if (i < CR - 2) ga = gp[(i + 2) * G3];                           \
            GATE_STEP(ge, whh1, bh1, hv);                                    \
            if (i < CR - 2) gbv = gp[(i + 3) * G3];                          \
            GATE_STEP(go, whh1, bh1, hv);                                    \
        }                                                                    \
    } while (0)

    // ---------------- pipelined chunk loop ----------------
    #pragma unroll 1
    for (int c = 0; c < NCHUNK; ++c) {
        if (!is_enc) {
            const int rbase = b * SEQ + c * CR;
            float* gdst = &gbuf[c & 1][0][0];
            const float4* xp4 = (const float4*)psh;
            #pragma unroll 1
            for (int g = 0; g < CR / 8; ++g) {
                int ohv[8];
                #pragma unroll
                for (int n = 0; n < 8; n++)
                    ohv[n] = oh[(rbase + 8 * g + n) * 4 + ohc];
                float valv[8];
                #pragma unroll
                for (int n = 0; n < 8; n++) {
                    int R = rbase + 8 * g + n;
                    int off = from_x ? (R * 12) : (ohv[n] << eshift);
                    valv[n] = pa[off];
                }
                #pragma unroll
                for (int n = 0; n < 8; n++) {
                    const int i = 8 * g + n;
                    const size_t R = (size_t)(rbase + i);
                    psh[lane] = valv[n];              // same-wave DS ordering
                    if (lane < FDIM) origin[R * FDIM + lane] = valv[n];
                    v2f a0 = {bi1, 0.f}, a1 = {0.f, 0.f};
                    #pragma unroll
                    for (int q = 0; q < 9; q++) {
                        float4 xv4 = xp4[q];
                        v2f xlo = {xv4.x, xv4.y}, xhi = {xv4.z, xv4.w};
                        a0 = __builtin_elementwise_fma(w1p[2*q],     xlo, a0);
                        a1 = __builtin_elementwise_fma(w1p[2*q + 1], xhi, a1);
                    }
                    float gg = (a0.x + a1.x) + (a0.y + a1.y);
                    if (lane < G3) gdst[i * G3 + lane] = gg;
                }
            }
        } else if (c > 0) {
            CONSUME_CHUNK((c - 1) & 1);
        }
        __syncthreads();
    }
    if (!is_enc) return;              // producer done (after its final barrier)

    CONSUME_CHUNK((NCHUNK - 1) & 1);  // last chunk; no further barriers

    // ---- decoder weights loaded only now (live range does not span chunk loop) ----
    const int kf = lane < FDIM ? lane : FDIM - 1;
    float whh2[HID], wfc[HID], wih2s[FDIM];
    #pragma unroll
    for (int q = 0; q < FDIM; q++) wih2s[q] = Wih2g[k * FDIM + q];
    #pragma unroll
    for (int u = 0; u < HID; u++) whh2[u] = Whh2g[k * HID + u];
    #pragma unroll
    for (int u = 0; u < HID; u++) wfc[u] = Wfcg[kf * HID + u];
    const float bi2 = bih2g[k], bh2 = bhh2g[k];
    const float bf  = bfcg[kf];

    // ---------------- handoff ----------------
    float hvd = fast_tanh(hv);
    #pragma unroll
    for (int u = 0; u < HID; u++) hs[u] = READLANE_F(hvd, u);

    float* orow = out2 + ((size_t)b * SEQ + (SEQ - 1)) * FDIM;

    float xv;
    {
        float f0 = bf, f1 = 0.f, f2 = 0.f, f3 = 0.f;
        #pragma unroll
        for (int u = 0; u < HID; u += 4) {
            f0 = fmaf(wfc[u + 0], hs[u + 0], f0);
            f1 = fmaf(wfc[u + 1], hs[u + 1], f1);
            f2 = fmaf(wfc[u + 2], hs[u + 2], f2);
            f3 = fmaf(wfc[u + 3], hs[u + 3], f3);
        }
        xv = fast_tanh((f0 + f1) + (f2 + f3));
    }
    // R13 x-broadcast: 36 readlanes -> SGPRs (xv valid on lanes 0..35; lanes
    // >=36 hold the kf-clamped duplicate of lane 35, never read).
    float xs[FDIM];
    #pragma unroll
    for (int f = 0; f < FDIM; f++) xs[f] = READLANE_F(xv, f);
    if (lane < FDIM) orow[lane] = xv;

    // ---------------- decoder (readlane-h, readlane-x, zero LDS traffic) ----
    #pragma unroll 1
    for (int d = 1; d < SEQ; ++d) {
        orow -= FDIM;
        // gh dot (overlaps nothing on the chain start; hs ready from prev step)
        float h0 = bh2, h1 = 0.f, h2 = 0.f, h3 = 0.f;
        #pragma unroll
        for (int u = 0; u < HID; u += 4) {
            h0 = fmaf(whh2[u + 0], hs[u + 0], h0);
            h1 = fmaf(whh2[u + 1], hs[u + 1], h1);
            h2 = fmaf(whh2[u + 2], hs[u + 2], h2);
            h3 = fmaf(whh2[u + 3], hs[u + 3], h3);
        }
        float gh = (h0 + h1) + (h2 + h3);
        // gi dot from SGPR-broadcast x (VGPR*SGPR FMAs, 4 accumulators)
        float c0 = bi2, c1 = 0.f, c2 = 0.f, c3 = 0.f;
        #pragma unroll
        for (int f = 0; f < FDIM; f += 4) {
            c0 = fmaf(wih2s[f + 0], xs[f + 0], c0);
            c1 = fmaf(wih2s[f + 1], xs[f + 1], c1);
            c2 = fmaf(wih2s[f + 2], xs[f + 2], c2);
            c3 = fmaf(wih2s[f + 3], xs[f + 3], c3);
        }
        float gi = (c0 + c1) + (c2 + c3);
        // gates (R6 exact form)
        float v   = gi + gh;
        float vz  = __shfl(v,  (lane + 20) & 63);
        float in_ = __shfl(gi, (lane + 40) & 63);
        float hn  = __shfl(gh, (lane + 40) & 63);
        float r = fast_sigmoid(v);
        float z = fast_sigmoid(vz);
        float n = fast_tanh(fmaf(r, hn, in_));
        float hraw = n + z * (hvd - n);
        hvd = fast_tanh(hraw);
        #pragma unroll
        for (int u = 0; u < HID; u++) hs[u] = READLANE_F(hvd, u);
        // FC -> new x
        float f0 = bf, f1 = 0.f, f2 = 0.f, f3 = 0.f;
        #pragma unroll
        for (int u = 0; u < HID; u += 4) {
            f0 = fmaf(wfc[u + 0], hs[u + 0], f0);
            f1 = fmaf(wfc[u + 1], hs[u + 1], f1);
            f2 = fmaf(wfc[u + 2], hs[u + 2], f2);
            f3 = fmaf(wfc[u + 3], hs[u + 3], f3);
        }
        xv = fast_tanh((f0 + f1) + (f2 + f3));
        // broadcast new x for next step; store after (store off-chain)
        #pragma unroll
        for (int f = 0; f < FDIM; f++) xs[f] = READLANE_F(xv, f);
        if (lane < FDIM) orow[lane] = xv;
    }
}

extern "C" void kernel_launch(void* const* d_in, const int* in_sizes, int n_in,
                              void* d_out, int out_size, void* d_ws, size_t ws_size,
                              hipStream_t stream) {
    const float* x    = (const float*)d_in[0];
    const int*   oh   = (const int*)d_in[1];
    const float* e0   = (const float*)d_in[2];
    const float* e1   = (const float*)d_in[3];
    const float* e2   = (const float*)d_in[4];
    const float* e3   = (const float*)d_in[5];
    const float* Wih1 = (const float*)d_in[6];
    const float* Whh1 = (const float*)d_in[7];
    const float* bih1 = (const float*)d_in[8];
    const float* bhh1 = (const float*)d_in[9];
    const float* Wih2 = (const float*)d_in[10];
    const float* Whh2 = (const float*)d_in[11];
    const float* bih2 = (const float*)d_in[12];
    const float* bhh2 = (const float*)d_in[13];
    const float* Wfc  = (const float*)d_in[14];
    const float* bfc  = (const float*)d_in[15];

    float* out    = (float*)d_out;
    float* origin = out;                                // output 0: (B,S,F)
    float* out2   = out + (size_t)BATCH * SEQ * FDIM;   // output 1: (B,S,F)

    gru_fused<<<BATCH, 128, 0, stream>>>(x, oh, e0, e1, e2, e3,
                                         Wih1, Whh1, bih1, bhh1,
                                         Wih2, Whh2, bih2, bhh2,
                                         Wfc, bfc, origin, out2);
}